// Round 10
// baseline (445.029 us; speedup 1.0000x reference)
//
#include <hip/hip_runtime.h>

#define N_NODES 100000
#define N_EDGES 6400000
#define D 12

#define SLOG 7
#define SSZ  128                           // nodes per bucket
#define NB   ((N_NODES + SSZ - 1) / SSZ)   // 782 buckets
#define SBLK 256                           // partition blocks
#define STHR 512
#define SEPB (N_EDGES / SBLK)              // 25000 edges per block (exact)
#define CAPS 48                            // fixed slots per (bucket,block) region
#define OVMAX 65536                        // overflow list capacity

#define CHUNK 1792                         // strip slots per agg chunk
#define SPT   7                            // slots per thread (CHUNK/256)

// R4 mid-tier constants
#define NBLK 512
#define EPB  ((N_EDGES + NBLK - 1) / NBLK)
#define CAP4 2048
#define EPT4 (CAP4 / 256)

// ---- bf16 helpers ----------------------------------------------------------
__device__ __forceinline__ unsigned int f2bf(float f) {
    unsigned int u = __float_as_uint(f);
    return (u + 0x7fffu + ((u >> 16) & 1u)) >> 16;   // RTNE
}
__device__ __forceinline__ unsigned int pk2(float lo, float hi) {
    return (f2bf(hi) << 16) | f2bf(lo);
}
__device__ __forceinline__ float bflo(unsigned int u) { return __uint_as_float(u << 16); }
__device__ __forceinline__ float bfhi(unsigned int u) { return __uint_as_float(u & 0xffff0000u); }

// Prep: fp32 x [N,12] -> bf16 xb padded rows of 16 elems; also zero ov counter.
__global__ __launch_bounds__(256) void prep_kernel(
    const float* __restrict__ x, unsigned int* __restrict__ xb, int* ovctr)
{
    int i = blockIdx.x * 256 + threadIdx.x;
    if (i == 0 && ovctr) *ovctr = 0;
    if (i >= N_NODES) return;
    const float4* xr = (const float4*)(x) + (size_t)i * 3;
    float4 a = xr[0], b = xr[1], c = xr[2];
    unsigned int* o = xb + (size_t)i * 8;
    ((uint4*)o)[0] = make_uint4(pk2(a.x, a.y), pk2(a.z, a.w), pk2(b.x, b.y), pk2(b.z, b.w));
    ((uint2*)(o + 4))[0] = make_uint2(pk2(c.x, c.y), pk2(c.z, c.w));
}

// Single-pass scatter: fixed-capacity strip layout, 1 LDS atomic/edge.
// Region for (bucket k, block b) = strip[(k*SBLK+b)*CAPS ...], 192B.
__global__ __launch_bounds__(512) void scatter1_kernel(
    const int* __restrict__ ei, unsigned int* __restrict__ strip,
    int* __restrict__ cnt, uint2* __restrict__ ovbuf, int* __restrict__ ovctr)
{
    __shared__ int cur[NB];
    int t = threadIdx.x;
    int b = blockIdx.x;
    for (int i = t; i < NB; i += STHR) cur[i] = 0;
    __syncthreads();

    const int* dei = ei + N_EDGES;
    int start = b * SEPB;
    int end = start + SEPB;

    int e = start + t;
    while (e + 3 * STHR < end) {
        int s0 = ei[e], s1 = ei[e + STHR], s2 = ei[e + 2 * STHR], s3 = ei[e + 3 * STHR];
        int d0 = dei[e], d1 = dei[e + STHR], d2 = dei[e + 2 * STHR], d3 = dei[e + 3 * STHR];
        int k0 = d0 >> SLOG, k1 = d1 >> SLOG, k2 = d2 >> SLOG, k3 = d3 >> SLOG;
        int p0 = atomicAdd(&cur[k0], 1);
        int p1 = atomicAdd(&cur[k1], 1);
        int p2 = atomicAdd(&cur[k2], 1);
        int p3 = atomicAdd(&cur[k3], 1);
        if (p0 < CAPS) strip[((size_t)(k0 * SBLK + b)) * CAPS + p0] = ((unsigned)s0 << SLOG) | (unsigned)(d0 & (SSZ - 1));
        else { int ix = atomicAdd(ovctr, 1); if (ix < OVMAX) ovbuf[ix] = make_uint2((unsigned)s0, (unsigned)d0); }
        if (p1 < CAPS) strip[((size_t)(k1 * SBLK + b)) * CAPS + p1] = ((unsigned)s1 << SLOG) | (unsigned)(d1 & (SSZ - 1));
        else { int ix = atomicAdd(ovctr, 1); if (ix < OVMAX) ovbuf[ix] = make_uint2((unsigned)s1, (unsigned)d1); }
        if (p2 < CAPS) strip[((size_t)(k2 * SBLK + b)) * CAPS + p2] = ((unsigned)s2 << SLOG) | (unsigned)(d2 & (SSZ - 1));
        else { int ix = atomicAdd(ovctr, 1); if (ix < OVMAX) ovbuf[ix] = make_uint2((unsigned)s2, (unsigned)d2); }
        if (p3 < CAPS) strip[((size_t)(k3 * SBLK + b)) * CAPS + p3] = ((unsigned)s3 << SLOG) | (unsigned)(d3 & (SSZ - 1));
        else { int ix = atomicAdd(ovctr, 1); if (ix < OVMAX) ovbuf[ix] = make_uint2((unsigned)s3, (unsigned)d3); }
        e += 4 * STHR;
    }
    while (e < end) {
        int s = ei[e], d = dei[e];
        int k = d >> SLOG;
        int p = atomicAdd(&cur[k], 1);
        if (p < CAPS) strip[((size_t)(k * SBLK + b)) * CAPS + p] = ((unsigned)s << SLOG) | (unsigned)(d & (SSZ - 1));
        else { int ix = atomicAdd(ovctr, 1); if (ix < OVMAX) ovbuf[ix] = make_uint2((unsigned)s, (unsigned)d); }
        e += STHR;
    }
    __syncthreads();
    int* crow = cnt + (size_t)b * NB;
    for (int i = t; i < NB; i += STHR) crow[i] = cur[i];
}

// Agg over the strip: one block per bucket. Bucket's data = contiguous span of
// 256 aligned 48-slot segments. Batched linear loads (7/thread), wave-0
// shuffle scan (5 barriers/chunk), register accumulation (2 LDS atomics/edge).
__global__ __launch_bounds__(256) void agg_strip_kernel(
    const unsigned int* __restrict__ strip, const int* __restrict__ cntm,
    const uint2* __restrict__ ovbuf, const int* __restrict__ ovctr,
    const unsigned int* __restrict__ xb,
    const float* __restrict__ x, const float* __restrict__ Wl,
    const float* __restrict__ Wr, const float* __restrict__ bias,
    float* __restrict__ out)
{
    __shared__ float sWl[D * D], sWr[D * D], sb[D];
    __shared__ int cnt[SSZ];
    __shared__ int segbase[SSZ + 1];
    __shared__ int cursor[SSZ];
    __shared__ int cnt_tot[SSZ];
    __shared__ int seglen[SBLK];
    __shared__ uint2 ovstage[256];        // overflow staging (2 KB)
    __shared__ unsigned vals[CHUNK * 6];  // 42 KB; reused as red[] at the end

    int t = threadIdx.x;
    int k = blockIdx.x;                   // bucket id

    if (t < D * D) { sWl[t] = Wl[t]; sWr[t] = Wr[t]; }
    if (t < D) sb[t] = bias[t];
    if (t < SSZ) cnt_tot[t] = 0;

    if (t < SBLK) {
        int c = cntm[(size_t)t * NB + k];
        seglen[t] = c < CAPS ? c : CAPS;
    }
    __syncthreads();

    float acc[D];
#pragma unroll
    for (int d = 0; d < D; ++d) acc[d] = 0.f;

    int loc = t >> 1;
    int sub = t & 1;

    const unsigned int* kstrip = strip + (size_t)k * SBLK * CAPS;

    const int TOTS = SBLK * CAPS;         // 12288 slots -> 7 chunks
    for (int c0 = 0; c0 < TOTS; c0 += CHUNK) {
        int n = min(CHUNK, TOTS - c0);
        if (t < SSZ) cnt[t] = 0;
        __syncthreads();

        // Batched linear loads: slot v = c0 + t + 256q. Coalesced, 7 in flight.
        unsigned pe[SPT];
        bool va[SPT];
#pragma unroll
        for (int q = 0; q < SPT; ++q) {
            int j = t + 256 * q;
            int v = c0 + j;
            bool ok = j < n;
            int s = v / CAPS;
            int r = v - s * CAPS;
            va[q] = ok && (r < seglen[ok ? s : 0]);
            pe[q] = ok ? kstrip[v] : 0u;
        }
#pragma unroll
        for (int q = 0; q < SPT; ++q)
            if (va[q]) atomicAdd(&cnt[pe[q] & (SSZ - 1)], 1);
        __syncthreads();

        // Wave-0 shuffle scan of the 128 counters -> segbase (exclusive).
        if (t < 64) {
            int a = cnt[t];
            int bq = cnt[64 + t];
            int ia = a;
#pragma unroll
            for (int dd = 1; dd < 64; dd <<= 1) {
                int tmp = __shfl_up(ia, dd);
                if (t >= dd) ia += tmp;
            }
            int tot_a = __shfl(ia, 63);
            int ib = bq;
#pragma unroll
            for (int dd = 1; dd < 64; dd <<= 1) {
                int tmp = __shfl_up(ib, dd);
                if (t >= dd) ib += tmp;
            }
            segbase[t + 1] = ia;
            segbase[65 + t] = ib + tot_a;
            if (t == 0) segbase[0] = 0;
        }
        __syncthreads();
        if (t < SSZ) { cursor[t] = segbase[t]; cnt_tot[t] += cnt[t]; }
        __syncthreads();

        // Place: gather xb row (L2-hot), write node's LDS segment.
#pragma unroll
        for (int q = 0; q < SPT; ++q) {
            if (va[q]) {
                unsigned p = pe[q];
                int slot = atomicAdd(&cursor[p & (SSZ - 1)], 1);
                const unsigned* r = xb + (size_t)(p >> SLOG) * 8;
                uint2 q0 = ((const uint2*)r)[0];
                uint2 q1 = ((const uint2*)r)[1];
                uint2 q2 = ((const uint2*)r)[2];
                unsigned* vv = &vals[slot * 6];
                ((uint2*)vv)[0] = q0;
                ((uint2*)vv)[1] = q1;
                ((uint2*)vv)[2] = q2;
            }
        }
        __syncthreads();

        // Accumulate: thread (loc, sub) scans its node's segment in registers.
        int a0 = segbase[loc], a1 = segbase[loc + 1];
        for (int j = a0 + sub; j < a1; j += 2) {
            const unsigned* vv = &vals[j * 6];
            uint2 q0 = ((const uint2*)vv)[0];
            uint2 q1 = ((const uint2*)vv)[1];
            uint2 q2 = ((const uint2*)vv)[2];
            acc[0]  += bflo(q0.x); acc[1]  += bfhi(q0.x);
            acc[2]  += bflo(q0.y); acc[3]  += bfhi(q0.y);
            acc[4]  += bflo(q1.x); acc[5]  += bfhi(q1.x);
            acc[6]  += bflo(q1.y); acc[7]  += bfhi(q1.y);
            acc[8]  += bflo(q2.x); acc[9]  += bfhi(q2.x);
            acc[10] += bflo(q2.y); acc[11] += bfhi(q2.y);
        }
        __syncthreads();
    }

    // Overflow edges (~1e3 expected at CAPS=48): cooperative LDS staging,
    // owner thread (loc, sub==0) folds matches into acc.
    int novf = *ovctr;
    if (novf > OVMAX) novf = OVMAX;
    for (int base = 0; base < novf; base += 256) {
        int m = min(256, novf - base);
        if (t < m) ovstage[t] = ovbuf[base + t];
        __syncthreads();
        if (sub == 0) {
            int matches = 0;
            for (int j = 0; j < m; ++j) {
                uint2 eo = ovstage[j];
                if ((int)(eo.y >> SLOG) == k && (int)(eo.y & (SSZ - 1)) == loc) {
                    const unsigned* r = xb + (size_t)eo.x * 8;
                    uint2 q0 = ((const uint2*)r)[0];
                    uint2 q1 = ((const uint2*)r)[1];
                    uint2 q2 = ((const uint2*)r)[2];
                    acc[0]  += bflo(q0.x); acc[1]  += bfhi(q0.x);
                    acc[2]  += bflo(q0.y); acc[3]  += bfhi(q0.y);
                    acc[4]  += bflo(q1.x); acc[5]  += bfhi(q1.x);
                    acc[6]  += bflo(q1.y); acc[7]  += bfhi(q1.y);
                    acc[8]  += bflo(q2.x); acc[9]  += bfhi(q2.x);
                    acc[10] += bflo(q2.y); acc[11] += bfhi(q2.y);
                    ++matches;
                }
            }
            if (matches) atomicAdd(&cnt_tot[loc], matches);
        }
        __syncthreads();
    }

    // Reduce 2 partials per node via LDS overlay (stride 13 vs 32 banks).
    float* red = (float*)vals;   // 2*1664 = 3328 floats <= CHUNK*6 = 10752
#pragma unroll
    for (int d = 0; d < D; ++d) red[sub * 1664 + loc * 13 + d] = acc[d];
    __syncthreads();

    if (t < SSZ) {
        int node = k * SSZ + t;
        if (node < N_NODES) {
            float m[D];
#pragma unroll
            for (int d = 0; d < D; ++d)
                m[d] = red[t * 13 + d] + red[1664 + t * 13 + d];
            float inv = 1.f / fmaxf((float)cnt_tot[t], 1.f);
#pragma unroll
            for (int d = 0; d < D; ++d) m[d] *= inv;

            float xi[D];
            const float4* xr = (const float4*)(x) + (size_t)node * 3;
            float4 x0 = xr[0], x1 = xr[1], x2 = xr[2];
            xi[0] = x0.x; xi[1] = x0.y; xi[2]  = x0.z; xi[3]  = x0.w;
            xi[4] = x1.x; xi[5] = x1.y; xi[6]  = x1.z; xi[7]  = x1.w;
            xi[8] = x2.x; xi[9] = x2.y; xi[10] = x2.z; xi[11] = x2.w;

            float o[D];
#pragma unroll
            for (int oo = 0; oo < D; ++oo) {
                float a = sb[oo];
#pragma unroll
                for (int d = 0; d < D; ++d) {
                    a += m[d] * sWl[oo * D + d];
                    a += xi[d] * sWr[oo * D + d];
                }
                o[oo] = a;
            }
            float4* orow = (float4*)(out) + (size_t)node * 3;
            orow[0] = make_float4(o[0], o[1], o[2], o[3]);
            orow[1] = make_float4(o[4], o[5], o[6], o[7]);
            orow[2] = make_float4(o[8], o[9], o[10], o[11]);
        }
    }
}

// ================= R4 mid-tier (proven 272 us pipeline) =====================

__global__ __launch_bounds__(256) void hist_kernel(
    const int* __restrict__ ei, int* __restrict__ bins)
{
    __shared__ int h[NB];
    for (int i = threadIdx.x; i < NB; i += 256) h[i] = 0;
    __syncthreads();
    const int* dei = ei + N_EDGES;
    int start = blockIdx.x * EPB;
    int end = min(start + EPB, N_EDGES);
    int e = start + (int)threadIdx.x;
    while (e + 768 < end) {
        int d0 = dei[e], d1 = dei[e + 256], d2 = dei[e + 512], d3 = dei[e + 768];
        atomicAdd(&h[d0 >> SLOG], 1);
        atomicAdd(&h[d1 >> SLOG], 1);
        atomicAdd(&h[d2 >> SLOG], 1);
        atomicAdd(&h[d3 >> SLOG], 1);
        e += 1024;
    }
    while (e < end) { atomicAdd(&h[dei[e] >> SLOG], 1); e += 256; }
    __syncthreads();
    for (int i = threadIdx.x; i < NB; i += 256) {
        int c = h[i];
        if (c) atomicAdd(&bins[i], c);
    }
}

__global__ __launch_bounds__(1024) void scan_kernel(
    const int* __restrict__ bins, int* __restrict__ base, int* __restrict__ cursor)
{
    __shared__ int buf[1024];
    __shared__ int carry;
    int tid = threadIdx.x;
    if (tid == 0) carry = 0;
    __syncthreads();
    for (int c0 = 0; c0 < NB; c0 += 1024) {
        int i = c0 + tid;
        int v = (i < NB) ? bins[i] : 0;
        buf[tid] = v;
        __syncthreads();
        for (int o = 1; o < 1024; o <<= 1) {
            int t = (tid >= o) ? buf[tid - o] : 0;
            __syncthreads();
            buf[tid] += t;
            __syncthreads();
        }
        int excl = buf[tid] - v + carry;
        if (i < NB) { base[i] = excl; cursor[i] = excl; }
        __syncthreads();
        if (tid == 0) carry += buf[1023];
        __syncthreads();
    }
    if (tid == 0) base[NB] = N_EDGES;
}

__global__ __launch_bounds__(512) void scatter_sort_kernel(
    const int* __restrict__ ei, int* __restrict__ cursor,
    unsigned int* __restrict__ sorted)
{
    __shared__ int h[NB];
    for (int i = threadIdx.x; i < NB; i += STHR) h[i] = 0;
    __syncthreads();
    const int* dei = ei + N_EDGES;
    int start = blockIdx.x * SEPB;
    int end = min(start + SEPB, N_EDGES);
    int e = start + (int)threadIdx.x;
    while (e + 3 * STHR < end) {
        int d0 = dei[e], d1 = dei[e + STHR], d2 = dei[e + 2 * STHR], d3 = dei[e + 3 * STHR];
        atomicAdd(&h[d0 >> SLOG], 1);
        atomicAdd(&h[d1 >> SLOG], 1);
        atomicAdd(&h[d2 >> SLOG], 1);
        atomicAdd(&h[d3 >> SLOG], 1);
        e += 4 * STHR;
    }
    while (e < end) { atomicAdd(&h[dei[e] >> SLOG], 1); e += STHR; }
    __syncthreads();
    for (int i = threadIdx.x; i < NB; i += STHR) {
        int c = h[i];
        h[i] = c ? atomicAdd(&cursor[i], c) : 0;
    }
    __syncthreads();
    e = start + (int)threadIdx.x;
    while (e + 3 * STHR < end) {
        int s0 = ei[e], s1 = ei[e + STHR], s2 = ei[e + 2 * STHR], s3 = ei[e + 3 * STHR];
        int d0 = dei[e], d1 = dei[e + STHR], d2 = dei[e + 2 * STHR], d3 = dei[e + 3 * STHR];
        int p0 = atomicAdd(&h[d0 >> SLOG], 1);
        int p1 = atomicAdd(&h[d1 >> SLOG], 1);
        int p2 = atomicAdd(&h[d2 >> SLOG], 1);
        int p3 = atomicAdd(&h[d3 >> SLOG], 1);
        sorted[p0] = ((unsigned)s0 << SLOG) | (unsigned)(d0 & (SSZ - 1));
        sorted[p1] = ((unsigned)s1 << SLOG) | (unsigned)(d1 & (SSZ - 1));
        sorted[p2] = ((unsigned)s2 << SLOG) | (unsigned)(d2 & (SSZ - 1));
        sorted[p3] = ((unsigned)s3 << SLOG) | (unsigned)(d3 & (SSZ - 1));
        e += 4 * STHR;
    }
    while (e < end) {
        int s = ei[e], d = dei[e];
        int pos = atomicAdd(&h[d >> SLOG], 1);
        sorted[pos] = ((unsigned)s << SLOG) | (unsigned)(d & (SSZ - 1));
        e += STHR;
    }
}

__global__ __launch_bounds__(256) void agg_reg4_kernel(
    const unsigned int* __restrict__ sorted, const int* __restrict__ base,
    const unsigned int* __restrict__ xb,
    const float* __restrict__ x, const float* __restrict__ Wl,
    const float* __restrict__ Wr, const float* __restrict__ bias,
    float* __restrict__ out)
{
    __shared__ float sWl[D * D], sWr[D * D], sb[D];
    __shared__ int cnt[SSZ];
    __shared__ int sbuf[SSZ];
    __shared__ int segbase[SSZ + 1];
    __shared__ int cursor[SSZ];
    __shared__ int cnt_tot[SSZ];
    __shared__ unsigned vals[CAP4 * 6];

    int t = threadIdx.x;
    int b = blockIdx.x;

    if (t < D * D) { sWl[t] = Wl[t]; sWr[t] = Wr[t]; }
    if (t < D) sb[t] = bias[t];
    if (t < SSZ) cnt_tot[t] = 0;

    float acc[D];
#pragma unroll
    for (int d = 0; d < D; ++d) acc[d] = 0.f;

    int loc = t >> 1;
    int sub = t & 1;

    int start = base[b];
    int end = base[b + 1];

    for (int c0 = start; c0 < end; c0 += CAP4) {
        int n = min(CAP4, end - c0);
        if (t < SSZ) cnt[t] = 0;
        __syncthreads();

        unsigned pe[EPT4];
        int ne = 0;
        for (int j = t; j < n; j += 256) pe[ne++] = sorted[c0 + j];
#pragma unroll
        for (int q = 0; q < EPT4; ++q)
            if (q < ne) atomicAdd(&cnt[pe[q] & (SSZ - 1)], 1);
        __syncthreads();

        if (t < SSZ) sbuf[t] = cnt[t];
        __syncthreads();
        for (int o = 1; o < SSZ; o <<= 1) {
            int v = (t < SSZ && t >= o) ? sbuf[t - o] : 0;
            __syncthreads();
            if (t < SSZ) sbuf[t] += v;
            __syncthreads();
        }
        if (t < SSZ) {
            segbase[t + 1] = sbuf[t];
            if (t == 0) segbase[0] = 0;
        }
        __syncthreads();
        if (t < SSZ) { cursor[t] = segbase[t]; cnt_tot[t] += cnt[t]; }
        __syncthreads();

#pragma unroll
        for (int q = 0; q < EPT4; ++q) {
            if (q < ne) {
                unsigned p = pe[q];
                int slot = atomicAdd(&cursor[p & (SSZ - 1)], 1);
                const unsigned* r = xb + (size_t)(p >> SLOG) * 8;
                uint2 q0 = ((const uint2*)r)[0];
                uint2 q1 = ((const uint2*)r)[1];
                uint2 q2 = ((const uint2*)r)[2];
                unsigned* vv = &vals[slot * 6];
                ((uint2*)vv)[0] = q0;
                ((uint2*)vv)[1] = q1;
                ((uint2*)vv)[2] = q2;
            }
        }
        __syncthreads();

        int a0 = segbase[loc], a1 = segbase[loc + 1];
        for (int j = a0 + sub; j < a1; j += 2) {
            const unsigned* vv = &vals[j * 6];
            uint2 q0 = ((const uint2*)vv)[0];
            uint2 q1 = ((const uint2*)vv)[1];
            uint2 q2 = ((const uint2*)vv)[2];
            acc[0]  += bflo(q0.x); acc[1]  += bfhi(q0.x);
            acc[2]  += bflo(q0.y); acc[3]  += bfhi(q0.y);
            acc[4]  += bflo(q1.x); acc[5]  += bfhi(q1.x);
            acc[6]  += bflo(q1.y); acc[7]  += bfhi(q1.y);
            acc[8]  += bflo(q2.x); acc[9]  += bfhi(q2.x);
            acc[10] += bflo(q2.y); acc[11] += bfhi(q2.y);
        }
        __syncthreads();
    }

    float* red = (float*)vals;
#pragma unroll
    for (int d = 0; d < D; ++d) red[sub * 1664 + loc * 13 + d] = acc[d];
    __syncthreads();

    if (t < SSZ) {
        int node = b * SSZ + t;
        if (node < N_NODES) {
            float m[D];
#pragma unroll
            for (int d = 0; d < D; ++d)
                m[d] = red[t * 13 + d] + red[1664 + t * 13 + d];
            float inv = 1.f / fmaxf((float)cnt_tot[t], 1.f);
#pragma unroll
            for (int d = 0; d < D; ++d) m[d] *= inv;

            float xi[D];
            const float4* xr = (const float4*)(x) + (size_t)node * 3;
            float4 x0 = xr[0], x1 = xr[1], x2 = xr[2];
            xi[0] = x0.x; xi[1] = x0.y; xi[2]  = x0.z; xi[3]  = x0.w;
            xi[4] = x1.x; xi[5] = x1.y; xi[6]  = x1.z; xi[7]  = x1.w;
            xi[8] = x2.x; xi[9] = x2.y; xi[10] = x2.z; xi[11] = x2.w;

            float o[D];
#pragma unroll
            for (int oo = 0; oo < D; ++oo) {
                float a = sb[oo];
#pragma unroll
                for (int d = 0; d < D; ++d) {
                    a += m[d] * sWl[oo * D + d];
                    a += xi[d] * sWr[oo * D + d];
                }
                o[oo] = a;
            }
            float4* orow = (float4*)(out) + (size_t)node * 3;
            orow[0] = make_float4(o[0], o[1], o[2], o[3]);
            orow[1] = make_float4(o[4], o[5], o[6], o[7]);
            orow[2] = make_float4(o[8], o[9], o[10], o[11]);
        }
    }
}

// ---------------- Last-resort fallback: global atomics ----------------------

__global__ __launch_bounds__(256) void scatter_kernel(
    const int* __restrict__ ei, const float* __restrict__ x,
    float* __restrict__ agg, float* __restrict__ cnt)
{
    int e = blockIdx.x * blockDim.x + threadIdx.x;
    if (e >= N_EDGES) return;
    int src = ei[e];
    int dst = ei[N_EDGES + e];
    const float4* xr = (const float4*)(x + (size_t)src * D);
    float4 a = xr[0], b4 = xr[1], c = xr[2];
    float* dr = agg + (size_t)dst * D;
    atomicAdd(dr + 0,  a.x);  atomicAdd(dr + 1,  a.y);
    atomicAdd(dr + 2,  a.z);  atomicAdd(dr + 3,  a.w);
    atomicAdd(dr + 4,  b4.x); atomicAdd(dr + 5,  b4.y);
    atomicAdd(dr + 6,  b4.z); atomicAdd(dr + 7,  b4.w);
    atomicAdd(dr + 8,  c.x);  atomicAdd(dr + 9,  c.y);
    atomicAdd(dr + 10, c.z);  atomicAdd(dr + 11, c.w);
    atomicAdd(cnt + dst, 1.0f);
}

__global__ __launch_bounds__(256) void finalize_kernel(
    const float* __restrict__ x, const float* __restrict__ Wl,
    const float* __restrict__ Wr, const float* __restrict__ bias,
    const float* __restrict__ agg, const float* __restrict__ cnt,
    float* __restrict__ out)
{
    __shared__ float sWl[D * D], sWr[D * D], sb[D];
    int t = threadIdx.x;
    if (t < D * D) { sWl[t] = Wl[t]; sWr[t] = Wr[t]; }
    if (t < D) sb[t] = bias[t];
    __syncthreads();
    int i = blockIdx.x * blockDim.x + t;
    if (i >= N_NODES) return;
    float inv = 1.0f / fmaxf(cnt[i], 1.0f);
    float m[D], xi[D];
    const float4* ar = (const float4*)(agg + (size_t)i * D);
    const float4* xr = (const float4*)(x + (size_t)i * D);
    float4 a0 = ar[0], a1 = ar[1], a2 = ar[2];
    float4 x0 = xr[0], x1 = xr[1], x2 = xr[2];
    m[0] = a0.x * inv; m[1] = a0.y * inv; m[2]  = a0.z * inv; m[3]  = a0.w * inv;
    m[4] = a1.x * inv; m[5] = a1.y * inv; m[6]  = a1.z * inv; m[7]  = a1.w * inv;
    m[8] = a2.x * inv; m[9] = a2.y * inv; m[10] = a2.z * inv; m[11] = a2.w * inv;
    xi[0] = x0.x; xi[1] = x0.y; xi[2]  = x0.z; xi[3]  = x0.w;
    xi[4] = x1.x; xi[5] = x1.y; xi[6]  = x1.z; xi[7]  = x1.w;
    xi[8] = x2.x; xi[9] = x2.y; xi[10] = x2.z; xi[11] = x2.w;
    float o[D];
#pragma unroll
    for (int oo = 0; oo < D; ++oo) {
        float acc = sb[oo];
#pragma unroll
        for (int d = 0; d < D; ++d) {
            acc += m[d] * sWl[oo * D + d];
            acc += xi[d] * sWr[oo * D + d];
        }
        o[oo] = acc;
    }
    float4* orow = (float4*)(out + (size_t)i * D);
    orow[0] = make_float4(o[0], o[1], o[2], o[3]);
    orow[1] = make_float4(o[4], o[5], o[6], o[7]);
    orow[2] = make_float4(o[8], o[9], o[10], o[11]);
}

extern "C" void kernel_launch(void* const* d_in, const int* in_sizes, int n_in,
                              void* d_out, int out_size, void* d_ws, size_t ws_size,
                              hipStream_t stream) {
    const float* x    = (const float*)d_in[0];
    const float* Wl   = (const float*)d_in[1];
    const float* Wr   = (const float*)d_in[2];
    const float* bias = (const float*)d_in[3];
    const int*   ei   = (const int*)d_in[4];
    float* out = (float*)d_out;

    size_t stripBytes  = (size_t)NB * SBLK * CAPS * sizeof(unsigned int); // 38.4 MB
    size_t xbBytes     = (size_t)N_NODES * 8 * sizeof(unsigned int);      // 3.2 MB
    size_t cntBytes    = (size_t)SBLK * NB * sizeof(int);                 // 0.8 MB
    size_t ovBytes     = (size_t)OVMAX * sizeof(uint2);                   // 0.5 MB
    size_t neededNew   = stripBytes + xbBytes + cntBytes + ovBytes + 64;

    size_t sortedBytes = (size_t)N_EDGES * sizeof(unsigned int);          // 25.6 MB
    size_t binsBytes   = (size_t)NB * sizeof(int);
    size_t baseBytes   = (size_t)(NB + 1) * sizeof(int);
    size_t neededMid   = sortedBytes + xbBytes + binsBytes + baseBytes + binsBytes;
    size_t neededLast  = ((size_t)N_NODES * D + N_NODES) * sizeof(float);

    if (ws_size >= neededNew) {
        char* p = (char*)d_ws;
        unsigned int* strip = (unsigned int*)p;         p += stripBytes;
        unsigned int* xb    = (unsigned int*)p;         p += xbBytes;
        int* cnt    = (int*)p;                          p += cntBytes;
        uint2* ovbuf = (uint2*)p;                       p += ovBytes;
        int* ovctr  = (int*)p;

        prep_kernel<<<(N_NODES + 255) / 256, 256, 0, stream>>>(x, xb, ovctr);
        scatter1_kernel<<<SBLK, STHR, 0, stream>>>(ei, strip, cnt, ovbuf, ovctr);
        agg_strip_kernel<<<NB, 256, 0, stream>>>(strip, cnt, ovbuf, ovctr, xb, x, Wl, Wr, bias, out);
    } else if (ws_size >= neededMid) {
        char* p = (char*)d_ws;
        unsigned int* sorted = (unsigned int*)p;        p += sortedBytes;
        unsigned int* xb     = (unsigned int*)p;        p += xbBytes;
        int* bins   = (int*)p;                          p += binsBytes;
        int* base   = (int*)p;                          p += baseBytes;
        int* cursor = (int*)p;

        hipMemsetAsync(bins, 0, binsBytes, stream);
        prep_kernel<<<(N_NODES + 255) / 256, 256, 0, stream>>>(x, xb, nullptr);
        hist_kernel<<<NBLK, 256, 0, stream>>>(ei, bins);
        scan_kernel<<<1, 1024, 0, stream>>>(bins, base, cursor);
        scatter_sort_kernel<<<SBLK, STHR, 0, stream>>>(ei, cursor, sorted);
        agg_reg4_kernel<<<NB, 256, 0, stream>>>(sorted, base, xb, x, Wl, Wr, bias, out);
    } else {
        float* agg = (float*)d_ws;
        float* cnt = agg + (size_t)N_NODES * D;
        hipMemsetAsync(d_ws, 0, neededLast, stream);
        scatter_kernel<<<(N_EDGES + 255) / 256, 256, 0, stream>>>(ei, x, agg, cnt);
        finalize_kernel<<<(N_NODES + 255) / 256, 256, 0, stream>>>(x, Wl, Wr, bias, agg, cnt, out);
    }
}

// Round 11
// 268.904 us; speedup vs baseline: 1.6550x; 1.6550x over previous
//
#include <hip/hip_runtime.h>

#define N_NODES 100000
#define N_EDGES 6400000
#define D 12

#define SLOG 7
#define SSZ  128                           // nodes per bucket
#define NB   ((N_NODES + SSZ - 1) / SSZ)   // 782 buckets
#define SBLK 256                           // partition blocks
#define STHR 512
#define SEPB (N_EDGES / SBLK)              // 25000 edges per block (exact)
#define CAPS 64                            // fixed slots per (bucket,block) region
#define OVMAX 65536                        // overflow list capacity

#define CHUNK 1792                         // strip slots per agg chunk
#define SPT   7                            // slots per thread (CHUNK/256)

// R4 mid-tier constants
#define NBLK 512
#define EPB  ((N_EDGES + NBLK - 1) / NBLK)
#define CAP4 2048
#define EPT4 (CAP4 / 256)

// ---- bf16 helpers ----------------------------------------------------------
__device__ __forceinline__ unsigned int f2bf(float f) {
    unsigned int u = __float_as_uint(f);
    return (u + 0x7fffu + ((u >> 16) & 1u)) >> 16;   // RTNE
}
__device__ __forceinline__ unsigned int pk2(float lo, float hi) {
    return (f2bf(hi) << 16) | f2bf(lo);
}
__device__ __forceinline__ float bflo(unsigned int u) { return __uint_as_float(u << 16); }
__device__ __forceinline__ float bfhi(unsigned int u) { return __uint_as_float(u & 0xffff0000u); }

// Prep: fp32 x [N,12] -> bf16 xb padded rows of 16 elems; also zero ov counter.
__global__ __launch_bounds__(256) void prep_kernel(
    const float* __restrict__ x, unsigned int* __restrict__ xb, int* ovctr)
{
    int i = blockIdx.x * 256 + threadIdx.x;
    if (i == 0 && ovctr) *ovctr = 0;
    if (i >= N_NODES) return;
    const float4* xr = (const float4*)(x) + (size_t)i * 3;
    float4 a = xr[0], b = xr[1], c = xr[2];
    unsigned int* o = xb + (size_t)i * 8;
    ((uint4*)o)[0] = make_uint4(pk2(a.x, a.y), pk2(a.z, a.w), pk2(b.x, b.y), pk2(b.z, b.w));
    ((uint2*)(o + 4))[0] = make_uint2(pk2(c.x, c.y), pk2(c.z, c.w));
}

// Single-pass scatter: fixed-capacity strip layout, 1 LDS atomic/edge.
// Region for (bucket k, block b) = strip[(k*SBLK+b)*CAPS ...], 256B aligned.
__global__ __launch_bounds__(512) void scatter1_kernel(
    const int* __restrict__ ei, unsigned int* __restrict__ strip,
    int* __restrict__ cnt, uint2* __restrict__ ovbuf, int* __restrict__ ovctr)
{
    __shared__ int cur[NB];
    int t = threadIdx.x;
    int b = blockIdx.x;
    for (int i = t; i < NB; i += STHR) cur[i] = 0;
    __syncthreads();

    const int* dei = ei + N_EDGES;
    int start = b * SEPB;
    int end = start + SEPB;

    int e = start + t;
    while (e + 3 * STHR < end) {
        int s0 = ei[e], s1 = ei[e + STHR], s2 = ei[e + 2 * STHR], s3 = ei[e + 3 * STHR];
        int d0 = dei[e], d1 = dei[e + STHR], d2 = dei[e + 2 * STHR], d3 = dei[e + 3 * STHR];
        int k0 = d0 >> SLOG, k1 = d1 >> SLOG, k2 = d2 >> SLOG, k3 = d3 >> SLOG;
        int p0 = atomicAdd(&cur[k0], 1);
        int p1 = atomicAdd(&cur[k1], 1);
        int p2 = atomicAdd(&cur[k2], 1);
        int p3 = atomicAdd(&cur[k3], 1);
        if (p0 < CAPS) strip[((size_t)(k0 * SBLK + b)) * CAPS + p0] = ((unsigned)s0 << SLOG) | (unsigned)(d0 & (SSZ - 1));
        else { int ix = atomicAdd(ovctr, 1); if (ix < OVMAX) ovbuf[ix] = make_uint2((unsigned)s0, (unsigned)d0); }
        if (p1 < CAPS) strip[((size_t)(k1 * SBLK + b)) * CAPS + p1] = ((unsigned)s1 << SLOG) | (unsigned)(d1 & (SSZ - 1));
        else { int ix = atomicAdd(ovctr, 1); if (ix < OVMAX) ovbuf[ix] = make_uint2((unsigned)s1, (unsigned)d1); }
        if (p2 < CAPS) strip[((size_t)(k2 * SBLK + b)) * CAPS + p2] = ((unsigned)s2 << SLOG) | (unsigned)(d2 & (SSZ - 1));
        else { int ix = atomicAdd(ovctr, 1); if (ix < OVMAX) ovbuf[ix] = make_uint2((unsigned)s2, (unsigned)d2); }
        if (p3 < CAPS) strip[((size_t)(k3 * SBLK + b)) * CAPS + p3] = ((unsigned)s3 << SLOG) | (unsigned)(d3 & (SSZ - 1));
        else { int ix = atomicAdd(ovctr, 1); if (ix < OVMAX) ovbuf[ix] = make_uint2((unsigned)s3, (unsigned)d3); }
        e += 4 * STHR;
    }
    while (e < end) {
        int s = ei[e], d = dei[e];
        int k = d >> SLOG;
        int p = atomicAdd(&cur[k], 1);
        if (p < CAPS) strip[((size_t)(k * SBLK + b)) * CAPS + p] = ((unsigned)s << SLOG) | (unsigned)(d & (SSZ - 1));
        else { int ix = atomicAdd(ovctr, 1); if (ix < OVMAX) ovbuf[ix] = make_uint2((unsigned)s, (unsigned)d); }
        e += STHR;
    }
    __syncthreads();
    int* crow = cnt + (size_t)b * NB;
    for (int i = t; i < NB; i += STHR) crow[i] = cur[i];
}

// Agg over the strip: one block per bucket. Bucket's data = contiguous 64KB
// span of 256 aligned 64-slot segments. Batched linear loads (7/thread, R4
// idiom), validity-guarded atomics, count/scan/place/register-accumulate core.
__global__ __launch_bounds__(256) void agg_strip_kernel(
    const unsigned int* __restrict__ strip, const int* __restrict__ cntm,
    const uint2* __restrict__ ovbuf, const int* __restrict__ ovctr,
    const unsigned int* __restrict__ xb,
    const float* __restrict__ x, const float* __restrict__ Wl,
    const float* __restrict__ Wr, const float* __restrict__ bias,
    float* __restrict__ out)
{
    __shared__ float sWl[D * D], sWr[D * D], sb[D];
    __shared__ int cnt[SSZ];
    __shared__ int sbuf[SSZ];
    __shared__ int segbase[SSZ + 1];
    __shared__ int cursor[SSZ];
    __shared__ int cnt_tot[SSZ];
    __shared__ int seglen[SBLK];
    __shared__ unsigned vals[CHUNK * 6];  // 42 KB; reused as red[] at the end

    int t = threadIdx.x;
    int k = blockIdx.x;                   // bucket id

    if (t < D * D) { sWl[t] = Wl[t]; sWr[t] = Wr[t]; }
    if (t < D) sb[t] = bias[t];
    if (t < SSZ) cnt_tot[t] = 0;

    // Segment lengths (clamped to staged capacity).
    if (t < SBLK) {
        int c = cntm[(size_t)t * NB + k];
        seglen[t] = c < CAPS ? c : CAPS;
    }
    __syncthreads();

    float acc[D];
#pragma unroll
    for (int d = 0; d < D; ++d) acc[d] = 0.f;

    int loc = t >> 1;
    int sub = t & 1;

    const unsigned int* kstrip = strip + (size_t)k * SBLK * CAPS;  // 64KB span

    const int TOTS = SBLK * CAPS;         // 16384 slots
    for (int c0 = 0; c0 < TOTS; c0 += CHUNK) {
        int n = min(CHUNK, TOTS - c0);
        if (t < SSZ) cnt[t] = 0;
        __syncthreads();

        // Batched linear loads: slot v = c0 + t + 256q. Coalesced, 7 in flight.
        unsigned pe[SPT];
        bool va[SPT];
#pragma unroll
        for (int q = 0; q < SPT; ++q) {
            int j = t + 256 * q;
            int v = c0 + j;
            bool ok = j < n;
            int s = v >> 6;                // segment id (valid when ok)
            va[q] = ok && ((v & 63) < seglen[ok ? s : 0]);
            pe[q] = ok ? kstrip[v] : 0u;
        }
        // Count (guarded).
#pragma unroll
        for (int q = 0; q < SPT; ++q)
            if (va[q]) atomicAdd(&cnt[pe[q] & (SSZ - 1)], 1);
        __syncthreads();

        // Scan 128 counters.
        if (t < SSZ) sbuf[t] = cnt[t];
        __syncthreads();
        for (int o = 1; o < SSZ; o <<= 1) {
            int v = (t < SSZ && t >= o) ? sbuf[t - o] : 0;
            __syncthreads();
            if (t < SSZ) sbuf[t] += v;
            __syncthreads();
        }
        if (t < SSZ) {
            segbase[t + 1] = sbuf[t];
            if (t == 0) segbase[0] = 0;
        }
        __syncthreads();
        if (t < SSZ) { cursor[t] = segbase[t]; cnt_tot[t] += cnt[t]; }
        __syncthreads();

        // Place: gather xb row (L2-hot), write node's LDS segment.
#pragma unroll
        for (int q = 0; q < SPT; ++q) {
            if (va[q]) {
                unsigned p = pe[q];
                int slot = atomicAdd(&cursor[p & (SSZ - 1)], 1);
                const unsigned* r = xb + (size_t)(p >> SLOG) * 8;
                uint2 q0 = ((const uint2*)r)[0];
                uint2 q1 = ((const uint2*)r)[1];
                uint2 q2 = ((const uint2*)r)[2];
                unsigned* vv = &vals[slot * 6];
                ((uint2*)vv)[0] = q0;
                ((uint2*)vv)[1] = q1;
                ((uint2*)vv)[2] = q2;
            }
        }
        __syncthreads();

        // Accumulate: thread (loc, sub) scans its node's segment in registers.
        int a0 = segbase[loc], a1 = segbase[loc + 1];
        for (int j = a0 + sub; j < a1; j += 2) {
            const unsigned* vv = &vals[j * 6];
            uint2 q0 = ((const uint2*)vv)[0];
            uint2 q1 = ((const uint2*)vv)[1];
            uint2 q2 = ((const uint2*)vv)[2];
            acc[0]  += bflo(q0.x); acc[1]  += bfhi(q0.x);
            acc[2]  += bflo(q0.y); acc[3]  += bfhi(q0.y);
            acc[4]  += bflo(q1.x); acc[5]  += bfhi(q1.x);
            acc[6]  += bflo(q1.y); acc[7]  += bfhi(q1.y);
            acc[8]  += bflo(q2.x); acc[9]  += bfhi(q2.x);
            acc[10] += bflo(q2.y); acc[11] += bfhi(q2.y);
        }
        __syncthreads();
    }

    // Overflow edges (rare at CAPS=64): owner thread (loc, sub==0) folds them.
    int novf = *ovctr;
    if (novf > OVMAX) novf = OVMAX;
    if (sub == 0 && novf > 0) {
        int matches = 0;
        for (int j = 0; j < novf; ++j) {
            uint2 eo = ovbuf[j];
            if ((int)(eo.y >> SLOG) == k && (int)(eo.y & (SSZ - 1)) == loc) {
                const unsigned* r = xb + (size_t)eo.x * 8;
                uint2 q0 = ((const uint2*)r)[0];
                uint2 q1 = ((const uint2*)r)[1];
                uint2 q2 = ((const uint2*)r)[2];
                acc[0]  += bflo(q0.x); acc[1]  += bfhi(q0.x);
                acc[2]  += bflo(q0.y); acc[3]  += bfhi(q0.y);
                acc[4]  += bflo(q1.x); acc[5]  += bfhi(q1.x);
                acc[6]  += bflo(q1.y); acc[7]  += bfhi(q1.y);
                acc[8]  += bflo(q2.x); acc[9]  += bfhi(q2.x);
                acc[10] += bflo(q2.y); acc[11] += bfhi(q2.y);
                ++matches;
            }
        }
        if (matches) atomicAdd(&cnt_tot[loc], matches);
    }

    // Reduce 2 partials per node via LDS overlay (stride 13 vs 32 banks).
    float* red = (float*)vals;   // 2*1664 = 3328 floats <= CHUNK*6 = 10752
#pragma unroll
    for (int d = 0; d < D; ++d) red[sub * 1664 + loc * 13 + d] = acc[d];
    __syncthreads();

    if (t < SSZ) {
        int node = k * SSZ + t;
        if (node < N_NODES) {
            float m[D];
#pragma unroll
            for (int d = 0; d < D; ++d)
                m[d] = red[t * 13 + d] + red[1664 + t * 13 + d];
            float inv = 1.f / fmaxf((float)cnt_tot[t], 1.f);
#pragma unroll
            for (int d = 0; d < D; ++d) m[d] *= inv;

            float xi[D];
            const float4* xr = (const float4*)(x) + (size_t)node * 3;
            float4 x0 = xr[0], x1 = xr[1], x2 = xr[2];
            xi[0] = x0.x; xi[1] = x0.y; xi[2]  = x0.z; xi[3]  = x0.w;
            xi[4] = x1.x; xi[5] = x1.y; xi[6]  = x1.z; xi[7]  = x1.w;
            xi[8] = x2.x; xi[9] = x2.y; xi[10] = x2.z; xi[11] = x2.w;

            float o[D];
#pragma unroll
            for (int oo = 0; oo < D; ++oo) {
                float a = sb[oo];
#pragma unroll
                for (int d = 0; d < D; ++d) {
                    a += m[d] * sWl[oo * D + d];
                    a += xi[d] * sWr[oo * D + d];
                }
                o[oo] = a;
            }
            float4* orow = (float4*)(out) + (size_t)node * 3;
            orow[0] = make_float4(o[0], o[1], o[2], o[3]);
            orow[1] = make_float4(o[4], o[5], o[6], o[7]);
            orow[2] = make_float4(o[8], o[9], o[10], o[11]);
        }
    }
}

// ================= R4 mid-tier (proven 272 us pipeline) =====================

__global__ __launch_bounds__(256) void hist_kernel(
    const int* __restrict__ ei, int* __restrict__ bins)
{
    __shared__ int h[NB];
    for (int i = threadIdx.x; i < NB; i += 256) h[i] = 0;
    __syncthreads();
    const int* dei = ei + N_EDGES;
    int start = blockIdx.x * EPB;
    int end = min(start + EPB, N_EDGES);
    int e = start + (int)threadIdx.x;
    while (e + 768 < end) {
        int d0 = dei[e], d1 = dei[e + 256], d2 = dei[e + 512], d3 = dei[e + 768];
        atomicAdd(&h[d0 >> SLOG], 1);
        atomicAdd(&h[d1 >> SLOG], 1);
        atomicAdd(&h[d2 >> SLOG], 1);
        atomicAdd(&h[d3 >> SLOG], 1);
        e += 1024;
    }
    while (e < end) { atomicAdd(&h[dei[e] >> SLOG], 1); e += 256; }
    __syncthreads();
    for (int i = threadIdx.x; i < NB; i += 256) {
        int c = h[i];
        if (c) atomicAdd(&bins[i], c);
    }
}

__global__ __launch_bounds__(1024) void scan_kernel(
    const int* __restrict__ bins, int* __restrict__ base, int* __restrict__ cursor)
{
    __shared__ int buf[1024];
    __shared__ int carry;
    int tid = threadIdx.x;
    if (tid == 0) carry = 0;
    __syncthreads();
    for (int c0 = 0; c0 < NB; c0 += 1024) {
        int i = c0 + tid;
        int v = (i < NB) ? bins[i] : 0;
        buf[tid] = v;
        __syncthreads();
        for (int o = 1; o < 1024; o <<= 1) {
            int t = (tid >= o) ? buf[tid - o] : 0;
            __syncthreads();
            buf[tid] += t;
            __syncthreads();
        }
        int excl = buf[tid] - v + carry;
        if (i < NB) { base[i] = excl; cursor[i] = excl; }
        __syncthreads();
        if (tid == 0) carry += buf[1023];
        __syncthreads();
    }
    if (tid == 0) base[NB] = N_EDGES;
}

__global__ __launch_bounds__(512) void scatter_sort_kernel(
    const int* __restrict__ ei, int* __restrict__ cursor,
    unsigned int* __restrict__ sorted)
{
    __shared__ int h[NB];
    for (int i = threadIdx.x; i < NB; i += STHR) h[i] = 0;
    __syncthreads();
    const int* dei = ei + N_EDGES;
    int start = blockIdx.x * SEPB;
    int end = min(start + SEPB, N_EDGES);
    int e = start + (int)threadIdx.x;
    while (e + 3 * STHR < end) {
        int d0 = dei[e], d1 = dei[e + STHR], d2 = dei[e + 2 * STHR], d3 = dei[e + 3 * STHR];
        atomicAdd(&h[d0 >> SLOG], 1);
        atomicAdd(&h[d1 >> SLOG], 1);
        atomicAdd(&h[d2 >> SLOG], 1);
        atomicAdd(&h[d3 >> SLOG], 1);
        e += 4 * STHR;
    }
    while (e < end) { atomicAdd(&h[dei[e] >> SLOG], 1); e += STHR; }
    __syncthreads();
    for (int i = threadIdx.x; i < NB; i += STHR) {
        int c = h[i];
        h[i] = c ? atomicAdd(&cursor[i], c) : 0;
    }
    __syncthreads();
    e = start + (int)threadIdx.x;
    while (e + 3 * STHR < end) {
        int s0 = ei[e], s1 = ei[e + STHR], s2 = ei[e + 2 * STHR], s3 = ei[e + 3 * STHR];
        int d0 = dei[e], d1 = dei[e + STHR], d2 = dei[e + 2 * STHR], d3 = dei[e + 3 * STHR];
        int p0 = atomicAdd(&h[d0 >> SLOG], 1);
        int p1 = atomicAdd(&h[d1 >> SLOG], 1);
        int p2 = atomicAdd(&h[d2 >> SLOG], 1);
        int p3 = atomicAdd(&h[d3 >> SLOG], 1);
        sorted[p0] = ((unsigned)s0 << SLOG) | (unsigned)(d0 & (SSZ - 1));
        sorted[p1] = ((unsigned)s1 << SLOG) | (unsigned)(d1 & (SSZ - 1));
        sorted[p2] = ((unsigned)s2 << SLOG) | (unsigned)(d2 & (SSZ - 1));
        sorted[p3] = ((unsigned)s3 << SLOG) | (unsigned)(d3 & (SSZ - 1));
        e += 4 * STHR;
    }
    while (e < end) {
        int s = ei[e], d = dei[e];
        int pos = atomicAdd(&h[d >> SLOG], 1);
        sorted[pos] = ((unsigned)s << SLOG) | (unsigned)(d & (SSZ - 1));
        e += STHR;
    }
}

__global__ __launch_bounds__(256) void agg_reg4_kernel(
    const unsigned int* __restrict__ sorted, const int* __restrict__ base,
    const unsigned int* __restrict__ xb,
    const float* __restrict__ x, const float* __restrict__ Wl,
    const float* __restrict__ Wr, const float* __restrict__ bias,
    float* __restrict__ out)
{
    __shared__ float sWl[D * D], sWr[D * D], sb[D];
    __shared__ int cnt[SSZ];
    __shared__ int sbuf[SSZ];
    __shared__ int segbase[SSZ + 1];
    __shared__ int cursor[SSZ];
    __shared__ int cnt_tot[SSZ];
    __shared__ unsigned vals[CAP4 * 6];

    int t = threadIdx.x;
    int b = blockIdx.x;

    if (t < D * D) { sWl[t] = Wl[t]; sWr[t] = Wr[t]; }
    if (t < D) sb[t] = bias[t];
    if (t < SSZ) cnt_tot[t] = 0;

    float acc[D];
#pragma unroll
    for (int d = 0; d < D; ++d) acc[d] = 0.f;

    int loc = t >> 1;
    int sub = t & 1;

    int start = base[b];
    int end = base[b + 1];

    for (int c0 = start; c0 < end; c0 += CAP4) {
        int n = min(CAP4, end - c0);
        if (t < SSZ) cnt[t] = 0;
        __syncthreads();

        unsigned pe[EPT4];
        int ne = 0;
        for (int j = t; j < n; j += 256) pe[ne++] = sorted[c0 + j];
#pragma unroll
        for (int q = 0; q < EPT4; ++q)
            if (q < ne) atomicAdd(&cnt[pe[q] & (SSZ - 1)], 1);
        __syncthreads();

        if (t < SSZ) sbuf[t] = cnt[t];
        __syncthreads();
        for (int o = 1; o < SSZ; o <<= 1) {
            int v = (t < SSZ && t >= o) ? sbuf[t - o] : 0;
            __syncthreads();
            if (t < SSZ) sbuf[t] += v;
            __syncthreads();
        }
        if (t < SSZ) {
            segbase[t + 1] = sbuf[t];
            if (t == 0) segbase[0] = 0;
        }
        __syncthreads();
        if (t < SSZ) { cursor[t] = segbase[t]; cnt_tot[t] += cnt[t]; }
        __syncthreads();

#pragma unroll
        for (int q = 0; q < EPT4; ++q) {
            if (q < ne) {
                unsigned p = pe[q];
                int slot = atomicAdd(&cursor[p & (SSZ - 1)], 1);
                const unsigned* r = xb + (size_t)(p >> SLOG) * 8;
                uint2 q0 = ((const uint2*)r)[0];
                uint2 q1 = ((const uint2*)r)[1];
                uint2 q2 = ((const uint2*)r)[2];
                unsigned* vv = &vals[slot * 6];
                ((uint2*)vv)[0] = q0;
                ((uint2*)vv)[1] = q1;
                ((uint2*)vv)[2] = q2;
            }
        }
        __syncthreads();

        int a0 = segbase[loc], a1 = segbase[loc + 1];
        for (int j = a0 + sub; j < a1; j += 2) {
            const unsigned* vv = &vals[j * 6];
            uint2 q0 = ((const uint2*)vv)[0];
            uint2 q1 = ((const uint2*)vv)[1];
            uint2 q2 = ((const uint2*)vv)[2];
            acc[0]  += bflo(q0.x); acc[1]  += bfhi(q0.x);
            acc[2]  += bflo(q0.y); acc[3]  += bfhi(q0.y);
            acc[4]  += bflo(q1.x); acc[5]  += bfhi(q1.x);
            acc[6]  += bflo(q1.y); acc[7]  += bfhi(q1.y);
            acc[8]  += bflo(q2.x); acc[9]  += bfhi(q2.x);
            acc[10] += bflo(q2.y); acc[11] += bfhi(q2.y);
        }
        __syncthreads();
    }

    float* red = (float*)vals;
#pragma unroll
    for (int d = 0; d < D; ++d) red[sub * 1664 + loc * 13 + d] = acc[d];
    __syncthreads();

    if (t < SSZ) {
        int node = b * SSZ + t;
        if (node < N_NODES) {
            float m[D];
#pragma unroll
            for (int d = 0; d < D; ++d)
                m[d] = red[t * 13 + d] + red[1664 + t * 13 + d];
            float inv = 1.f / fmaxf((float)cnt_tot[t], 1.f);
#pragma unroll
            for (int d = 0; d < D; ++d) m[d] *= inv;

            float xi[D];
            const float4* xr = (const float4*)(x) + (size_t)node * 3;
            float4 x0 = xr[0], x1 = xr[1], x2 = xr[2];
            xi[0] = x0.x; xi[1] = x0.y; xi[2]  = x0.z; xi[3]  = x0.w;
            xi[4] = x1.x; xi[5] = x1.y; xi[6]  = x1.z; xi[7]  = x1.w;
            xi[8] = x2.x; xi[9] = x2.y; xi[10] = x2.z; xi[11] = x2.w;

            float o[D];
#pragma unroll
            for (int oo = 0; oo < D; ++oo) {
                float a = sb[oo];
#pragma unroll
                for (int d = 0; d < D; ++d) {
                    a += m[d] * sWl[oo * D + d];
                    a += xi[d] * sWr[oo * D + d];
                }
                o[oo] = a;
            }
            float4* orow = (float4*)(out) + (size_t)node * 3;
            orow[0] = make_float4(o[0], o[1], o[2], o[3]);
            orow[1] = make_float4(o[4], o[5], o[6], o[7]);
            orow[2] = make_float4(o[8], o[9], o[10], o[11]);
        }
    }
}

// ---------------- Last-resort fallback: global atomics ----------------------

__global__ __launch_bounds__(256) void scatter_kernel(
    const int* __restrict__ ei, const float* __restrict__ x,
    float* __restrict__ agg, float* __restrict__ cnt)
{
    int e = blockIdx.x * blockDim.x + threadIdx.x;
    if (e >= N_EDGES) return;
    int src = ei[e];
    int dst = ei[N_EDGES + e];
    const float4* xr = (const float4*)(x + (size_t)src * D);
    float4 a = xr[0], b4 = xr[1], c = xr[2];
    float* dr = agg + (size_t)dst * D;
    atomicAdd(dr + 0,  a.x);  atomicAdd(dr + 1,  a.y);
    atomicAdd(dr + 2,  a.z);  atomicAdd(dr + 3,  a.w);
    atomicAdd(dr + 4,  b4.x); atomicAdd(dr + 5,  b4.y);
    atomicAdd(dr + 6,  b4.z); atomicAdd(dr + 7,  b4.w);
    atomicAdd(dr + 8,  c.x);  atomicAdd(dr + 9,  c.y);
    atomicAdd(dr + 10, c.z);  atomicAdd(dr + 11, c.w);
    atomicAdd(cnt + dst, 1.0f);
}

__global__ __launch_bounds__(256) void finalize_kernel(
    const float* __restrict__ x, const float* __restrict__ Wl,
    const float* __restrict__ Wr, const float* __restrict__ bias,
    const float* __restrict__ agg, const float* __restrict__ cnt,
    float* __restrict__ out)
{
    __shared__ float sWl[D * D], sWr[D * D], sb[D];
    int t = threadIdx.x;
    if (t < D * D) { sWl[t] = Wl[t]; sWr[t] = Wr[t]; }
    if (t < D) sb[t] = bias[t];
    __syncthreads();
    int i = blockIdx.x * blockDim.x + t;
    if (i >= N_NODES) return;
    float inv = 1.0f / fmaxf(cnt[i], 1.0f);
    float m[D], xi[D];
    const float4* ar = (const float4*)(agg + (size_t)i * D);
    const float4* xr = (const float4*)(x + (size_t)i * D);
    float4 a0 = ar[0], a1 = ar[1], a2 = ar[2];
    float4 x0 = xr[0], x1 = xr[1], x2 = xr[2];
    m[0] = a0.x * inv; m[1] = a0.y * inv; m[2]  = a0.z * inv; m[3]  = a0.w * inv;
    m[4] = a1.x * inv; m[5] = a1.y * inv; m[6]  = a1.z * inv; m[7]  = a1.w * inv;
    m[8] = a2.x * inv; m[9] = a2.y * inv; m[10] = a2.z * inv; m[11] = a2.w * inv;
    xi[0] = x0.x; xi[1] = x0.y; xi[2]  = x0.z; xi[3]  = x0.w;
    xi[4] = x1.x; xi[5] = x1.y; xi[6]  = x1.z; xi[7]  = x1.w;
    xi[8] = x2.x; xi[9] = x2.y; xi[10] = x2.z; xi[11] = x2.w;
    float o[D];
#pragma unroll
    for (int oo = 0; oo < D; ++oo) {
        float acc = sb[oo];
#pragma unroll
        for (int d = 0; d < D; ++d) {
            acc += m[d] * sWl[oo * D + d];
            acc += xi[d] * sWr[oo * D + d];
        }
        o[oo] = acc;
    }
    float4* orow = (float4*)(out + (size_t)i * D);
    orow[0] = make_float4(o[0], o[1], o[2], o[3]);
    orow[1] = make_float4(o[4], o[5], o[6], o[7]);
    orow[2] = make_float4(o[8], o[9], o[10], o[11]);
}

extern "C" void kernel_launch(void* const* d_in, const int* in_sizes, int n_in,
                              void* d_out, int out_size, void* d_ws, size_t ws_size,
                              hipStream_t stream) {
    const float* x    = (const float*)d_in[0];
    const float* Wl   = (const float*)d_in[1];
    const float* Wr   = (const float*)d_in[2];
    const float* bias = (const float*)d_in[3];
    const int*   ei   = (const int*)d_in[4];
    float* out = (float*)d_out;

    size_t stripBytes  = (size_t)NB * SBLK * CAPS * sizeof(unsigned int); // 51.25 MB
    size_t xbBytes     = (size_t)N_NODES * 8 * sizeof(unsigned int);      // 3.2 MB
    size_t cntBytes    = (size_t)SBLK * NB * sizeof(int);                 // 0.8 MB
    size_t ovBytes     = (size_t)OVMAX * sizeof(uint2);                   // 0.5 MB
    size_t neededNew   = stripBytes + xbBytes + cntBytes + ovBytes + 64;

    size_t sortedBytes = (size_t)N_EDGES * sizeof(unsigned int);          // 25.6 MB
    size_t binsBytes   = (size_t)NB * sizeof(int);
    size_t baseBytes   = (size_t)(NB + 1) * sizeof(int);
    size_t neededMid   = sortedBytes + xbBytes + binsBytes + baseBytes + binsBytes;
    size_t neededLast  = ((size_t)N_NODES * D + N_NODES) * sizeof(float);

    if (ws_size >= neededNew) {
        char* p = (char*)d_ws;
        unsigned int* strip = (unsigned int*)p;         p += stripBytes;
        unsigned int* xb    = (unsigned int*)p;         p += xbBytes;
        int* cnt    = (int*)p;                          p += cntBytes;
        uint2* ovbuf = (uint2*)p;                       p += ovBytes;
        int* ovctr  = (int*)p;

        prep_kernel<<<(N_NODES + 255) / 256, 256, 0, stream>>>(x, xb, ovctr);
        scatter1_kernel<<<SBLK, STHR, 0, stream>>>(ei, strip, cnt, ovbuf, ovctr);
        agg_strip_kernel<<<NB, 256, 0, stream>>>(strip, cnt, ovbuf, ovctr, xb, x, Wl, Wr, bias, out);
    } else if (ws_size >= neededMid) {
        char* p = (char*)d_ws;
        unsigned int* sorted = (unsigned int*)p;        p += sortedBytes;
        unsigned int* xb     = (unsigned int*)p;        p += xbBytes;
        int* bins   = (int*)p;                          p += binsBytes;
        int* base   = (int*)p;                          p += baseBytes;
        int* cursor = (int*)p;

        hipMemsetAsync(bins, 0, binsBytes, stream);
        prep_kernel<<<(N_NODES + 255) / 256, 256, 0, stream>>>(x, xb, nullptr);
        hist_kernel<<<NBLK, 256, 0, stream>>>(ei, bins);
        scan_kernel<<<1, 1024, 0, stream>>>(bins, base, cursor);
        scatter_sort_kernel<<<SBLK, STHR, 0, stream>>>(ei, cursor, sorted);
        agg_reg4_kernel<<<NB, 256, 0, stream>>>(sorted, base, xb, x, Wl, Wr, bias, out);
    } else {
        float* agg = (float*)d_ws;
        float* cnt = agg + (size_t)N_NODES * D;
        hipMemsetAsync(d_ws, 0, neededLast, stream);
        scatter_kernel<<<(N_EDGES + 255) / 256, 256, 0, stream>>>(ei, x, agg, cnt);
        finalize_kernel<<<(N_NODES + 255) / 256, 256, 0, stream>>>(x, Wl, Wr, bias, agg, cnt, out);
    }
}

// Round 12
// 251.923 us; speedup vs baseline: 1.7665x; 1.0674x over previous
//
#include <hip/hip_runtime.h>

#define N_NODES 100000
#define N_EDGES 6400000
#define D 12

#define SLOG 7
#define SSZ  128                           // nodes per bucket
#define NB   ((N_NODES + SSZ - 1) / SSZ)   // 782 buckets
#define SBLK 256                           // partition blocks
#define STHR 512
#define SEPB (N_EDGES / SBLK)              // 25000 edges per block (exact)
#define CAPS 64                            // fixed slots per (bucket,block) region
#define OVMAX 65536                        // overflow list capacity

#define CHUNK 1792                         // strip slots per agg chunk
#define SPT   7                            // slots per thread (CHUNK/256)

// R4 mid-tier constants
#define NBLK 512
#define EPB  ((N_EDGES + NBLK - 1) / NBLK)
#define CAP4 2048
#define EPT4 (CAP4 / 256)

// ---- bf16 helpers ----------------------------------------------------------
__device__ __forceinline__ unsigned int f2bf(float f) {
    unsigned int u = __float_as_uint(f);
    return (u + 0x7fffu + ((u >> 16) & 1u)) >> 16;   // RTNE
}
__device__ __forceinline__ unsigned int pk2(float lo, float hi) {
    return (f2bf(hi) << 16) | f2bf(lo);
}
__device__ __forceinline__ float bflo(unsigned int u) { return __uint_as_float(u << 16); }
__device__ __forceinline__ float bfhi(unsigned int u) { return __uint_as_float(u & 0xffff0000u); }

// Prep: fp32 x [N,12] -> bf16 xb padded rows of 16 elems; also zero ov counter.
__global__ __launch_bounds__(256) void prep_kernel(
    const float* __restrict__ x, unsigned int* __restrict__ xb, int* ovctr)
{
    int i = blockIdx.x * 256 + threadIdx.x;
    if (i == 0 && ovctr) *ovctr = 0;
    if (i >= N_NODES) return;
    const float4* xr = (const float4*)(x) + (size_t)i * 3;
    float4 a = xr[0], b = xr[1], c = xr[2];
    unsigned int* o = xb + (size_t)i * 8;
    ((uint4*)o)[0] = make_uint4(pk2(a.x, a.y), pk2(a.z, a.w), pk2(b.x, b.y), pk2(b.z, b.w));
    ((uint2*)(o + 4))[0] = make_uint2(pk2(c.x, c.y), pk2(c.z, c.w));
}

// Single-pass scatter: fixed-capacity strip layout, 1 LDS atomic/edge.
// Region for (bucket k, block b) = strip[(k*SBLK+b)*CAPS ...], 256B aligned.
__global__ __launch_bounds__(512) void scatter1_kernel(
    const int* __restrict__ ei, unsigned int* __restrict__ strip,
    int* __restrict__ cnt, uint2* __restrict__ ovbuf, int* __restrict__ ovctr)
{
    __shared__ int cur[NB];
    int t = threadIdx.x;
    int b = blockIdx.x;
    for (int i = t; i < NB; i += STHR) cur[i] = 0;
    __syncthreads();

    const int* dei = ei + N_EDGES;
    int start = b * SEPB;
    int end = start + SEPB;

    int e = start + t;
    while (e + 3 * STHR < end) {
        int s0 = ei[e], s1 = ei[e + STHR], s2 = ei[e + 2 * STHR], s3 = ei[e + 3 * STHR];
        int d0 = dei[e], d1 = dei[e + STHR], d2 = dei[e + 2 * STHR], d3 = dei[e + 3 * STHR];
        int k0 = d0 >> SLOG, k1 = d1 >> SLOG, k2 = d2 >> SLOG, k3 = d3 >> SLOG;
        int p0 = atomicAdd(&cur[k0], 1);
        int p1 = atomicAdd(&cur[k1], 1);
        int p2 = atomicAdd(&cur[k2], 1);
        int p3 = atomicAdd(&cur[k3], 1);
        if (p0 < CAPS) strip[((size_t)(k0 * SBLK + b)) * CAPS + p0] = ((unsigned)s0 << SLOG) | (unsigned)(d0 & (SSZ - 1));
        else { int ix = atomicAdd(ovctr, 1); if (ix < OVMAX) ovbuf[ix] = make_uint2((unsigned)s0, (unsigned)d0); }
        if (p1 < CAPS) strip[((size_t)(k1 * SBLK + b)) * CAPS + p1] = ((unsigned)s1 << SLOG) | (unsigned)(d1 & (SSZ - 1));
        else { int ix = atomicAdd(ovctr, 1); if (ix < OVMAX) ovbuf[ix] = make_uint2((unsigned)s1, (unsigned)d1); }
        if (p2 < CAPS) strip[((size_t)(k2 * SBLK + b)) * CAPS + p2] = ((unsigned)s2 << SLOG) | (unsigned)(d2 & (SSZ - 1));
        else { int ix = atomicAdd(ovctr, 1); if (ix < OVMAX) ovbuf[ix] = make_uint2((unsigned)s2, (unsigned)d2); }
        if (p3 < CAPS) strip[((size_t)(k3 * SBLK + b)) * CAPS + p3] = ((unsigned)s3 << SLOG) | (unsigned)(d3 & (SSZ - 1));
        else { int ix = atomicAdd(ovctr, 1); if (ix < OVMAX) ovbuf[ix] = make_uint2((unsigned)s3, (unsigned)d3); }
        e += 4 * STHR;
    }
    while (e < end) {
        int s = ei[e], d = dei[e];
        int k = d >> SLOG;
        int p = atomicAdd(&cur[k], 1);
        if (p < CAPS) strip[((size_t)(k * SBLK + b)) * CAPS + p] = ((unsigned)s << SLOG) | (unsigned)(d & (SSZ - 1));
        else { int ix = atomicAdd(ovctr, 1); if (ix < OVMAX) ovbuf[ix] = make_uint2((unsigned)s, (unsigned)d); }
        e += STHR;
    }
    __syncthreads();
    int* crow = cnt + (size_t)b * NB;
    for (int i = t; i < NB; i += STHR) crow[i] = cur[i];
}

// Agg over the strip: one block per bucket, R11 core + REGISTER DOUBLE-BUFFER:
// chunk c+1's strip loads are issued at the start of chunk c's accumulate
// phase (longest barrier-free window), hiding HBM latency that was previously
// exposed at every chunk boundary by the barrier vmcnt(0) drain.
__global__ __launch_bounds__(256) void agg_strip_kernel(
    const unsigned int* __restrict__ strip, const int* __restrict__ cntm,
    const uint2* __restrict__ ovbuf, const int* __restrict__ ovctr,
    const unsigned int* __restrict__ xb,
    const float* __restrict__ x, const float* __restrict__ Wl,
    const float* __restrict__ Wr, const float* __restrict__ bias,
    float* __restrict__ out)
{
    __shared__ float sWl[D * D], sWr[D * D], sb[D];
    __shared__ int cnt[SSZ];
    __shared__ int sbuf[SSZ];
    __shared__ int segbase[SSZ + 1];
    __shared__ int cursor[SSZ];
    __shared__ int cnt_tot[SSZ];
    __shared__ int seglen[SBLK];
    __shared__ unsigned vals[CHUNK * 6];  // 42 KB; reused as red[] at the end

    int t = threadIdx.x;
    int k = blockIdx.x;                   // bucket id

    if (t < D * D) { sWl[t] = Wl[t]; sWr[t] = Wr[t]; }
    if (t < D) sb[t] = bias[t];
    if (t < SSZ) cnt_tot[t] = 0;

    // Segment lengths (clamped to staged capacity).
    if (t < SBLK) {
        int c = cntm[(size_t)t * NB + k];
        seglen[t] = c < CAPS ? c : CAPS;
    }
    __syncthreads();

    float acc[D];
#pragma unroll
    for (int d = 0; d < D; ++d) acc[d] = 0.f;

    int loc = t >> 1;
    int sub = t & 1;

    const unsigned int* kstrip = strip + (size_t)k * SBLK * CAPS;  // 64KB span
    const int TOTS = SBLK * CAPS;         // 16384 slots -> 10 chunks

// Load one chunk's slots into named register arrays (static indexing only).
#define LOADCH(C0, PE, VA)                                                  \
    {                                                                       \
        int n_ = min(CHUNK, TOTS - (C0));                                   \
        _Pragma("unroll")                                                   \
        for (int q = 0; q < SPT; ++q) {                                     \
            int j_ = t + 256 * q;                                           \
            int v_ = (C0) + j_;                                             \
            bool ok_ = j_ < n_;                                             \
            int s_ = v_ >> 6;                                               \
            VA[q] = ok_ && ((v_ & 63) < seglen[ok_ ? s_ : 0]);              \
            PE[q] = ok_ ? kstrip[v_] : 0u;                                  \
        }                                                                   \
    }

// Process one chunk; optionally prefetch the next chunk's registers at the
// start of the accumulate phase (after place's barrier).
#define PROCESS(PE, VA, DOPF, C0N, PEN, VAN)                                \
    {                                                                       \
        if (t < SSZ) cnt[t] = 0;                                            \
        __syncthreads();                                                    \
        _Pragma("unroll")                                                   \
        for (int q = 0; q < SPT; ++q)                                       \
            if (VA[q]) atomicAdd(&cnt[PE[q] & (SSZ - 1)], 1);               \
        __syncthreads();                                                    \
        if (t < SSZ) sbuf[t] = cnt[t];                                      \
        __syncthreads();                                                    \
        for (int o_ = 1; o_ < SSZ; o_ <<= 1) {                              \
            int v_ = (t < SSZ && t >= o_) ? sbuf[t - o_] : 0;               \
            __syncthreads();                                                \
            if (t < SSZ) sbuf[t] += v_;                                     \
            __syncthreads();                                                \
        }                                                                   \
        if (t < SSZ) {                                                      \
            segbase[t + 1] = sbuf[t];                                       \
            if (t == 0) segbase[0] = 0;                                     \
        }                                                                   \
        __syncthreads();                                                    \
        if (t < SSZ) { cursor[t] = segbase[t]; cnt_tot[t] += cnt[t]; }      \
        __syncthreads();                                                    \
        _Pragma("unroll")                                                   \
        for (int q = 0; q < SPT; ++q) {                                     \
            if (VA[q]) {                                                    \
                unsigned p_ = PE[q];                                        \
                int slot_ = atomicAdd(&cursor[p_ & (SSZ - 1)], 1);          \
                const unsigned* r_ = xb + (size_t)(p_ >> SLOG) * 8;         \
                uint2 q0_ = ((const uint2*)r_)[0];                          \
                uint2 q1_ = ((const uint2*)r_)[1];                          \
                uint2 q2_ = ((const uint2*)r_)[2];                          \
                unsigned* vv_ = &vals[slot_ * 6];                           \
                ((uint2*)vv_)[0] = q0_;                                     \
                ((uint2*)vv_)[1] = q1_;                                     \
                ((uint2*)vv_)[2] = q2_;                                     \
            }                                                               \
        }                                                                   \
        __syncthreads();                                                    \
        if (DOPF) LOADCH(C0N, PEN, VAN);   /* prefetch overlaps accumulate */ \
        {                                                                   \
            int a0_ = segbase[loc], a1_ = segbase[loc + 1];                 \
            for (int j_ = a0_ + sub; j_ < a1_; j_ += 2) {                   \
                const unsigned* vv_ = &vals[j_ * 6];                        \
                uint2 q0_ = ((const uint2*)vv_)[0];                         \
                uint2 q1_ = ((const uint2*)vv_)[1];                         \
                uint2 q2_ = ((const uint2*)vv_)[2];                         \
                acc[0]  += bflo(q0_.x); acc[1]  += bfhi(q0_.x);             \
                acc[2]  += bflo(q0_.y); acc[3]  += bfhi(q0_.y);             \
                acc[4]  += bflo(q1_.x); acc[5]  += bfhi(q1_.x);             \
                acc[6]  += bflo(q1_.y); acc[7]  += bfhi(q1_.y);             \
                acc[8]  += bflo(q2_.x); acc[9]  += bfhi(q2_.x);             \
                acc[10] += bflo(q2_.y); acc[11] += bfhi(q2_.y);             \
            }                                                               \
        }                                                                   \
        __syncthreads();                                                    \
    }

    unsigned peA[SPT], peB[SPT];
    bool vaA[SPT], vaB[SPT];
    const int NCH = (TOTS + CHUNK - 1) / CHUNK;   // 10

    LOADCH(0, peA, vaA);
    for (int ci = 0; ci < NCH; ci += 2) {
        bool hasB = (ci + 1) < NCH;
        bool hasA2 = (ci + 2) < NCH;
        PROCESS(peA, vaA, hasB, (ci + 1) * CHUNK, peB, vaB);
        if (hasB)
            PROCESS(peB, vaB, hasA2, (ci + 2) * CHUNK, peA, vaA);
    }
#undef PROCESS
#undef LOADCH

    // Overflow edges (rare at CAPS=64): owner thread (loc, sub==0) folds them.
    int novf = *ovctr;
    if (novf > OVMAX) novf = OVMAX;
    if (sub == 0 && novf > 0) {
        int matches = 0;
        for (int j = 0; j < novf; ++j) {
            uint2 eo = ovbuf[j];
            if ((int)(eo.y >> SLOG) == k && (int)(eo.y & (SSZ - 1)) == loc) {
                const unsigned* r = xb + (size_t)eo.x * 8;
                uint2 q0 = ((const uint2*)r)[0];
                uint2 q1 = ((const uint2*)r)[1];
                uint2 q2 = ((const uint2*)r)[2];
                acc[0]  += bflo(q0.x); acc[1]  += bfhi(q0.x);
                acc[2]  += bflo(q0.y); acc[3]  += bfhi(q0.y);
                acc[4]  += bflo(q1.x); acc[5]  += bfhi(q1.x);
                acc[6]  += bflo(q1.y); acc[7]  += bfhi(q1.y);
                acc[8]  += bflo(q2.x); acc[9]  += bfhi(q2.x);
                acc[10] += bflo(q2.y); acc[11] += bfhi(q2.y);
                ++matches;
            }
        }
        if (matches) atomicAdd(&cnt_tot[loc], matches);
    }

    // Reduce 2 partials per node via LDS overlay (stride 13 vs 32 banks).
    float* red = (float*)vals;   // 2*1664 = 3328 floats <= CHUNK*6 = 10752
#pragma unroll
    for (int d = 0; d < D; ++d) red[sub * 1664 + loc * 13 + d] = acc[d];
    __syncthreads();

    if (t < SSZ) {
        int node = k * SSZ + t;
        if (node < N_NODES) {
            float m[D];
#pragma unroll
            for (int d = 0; d < D; ++d)
                m[d] = red[t * 13 + d] + red[1664 + t * 13 + d];
            float inv = 1.f / fmaxf((float)cnt_tot[t], 1.f);
#pragma unroll
            for (int d = 0; d < D; ++d) m[d] *= inv;

            float xi[D];
            const float4* xr = (const float4*)(x) + (size_t)node * 3;
            float4 x0 = xr[0], x1 = xr[1], x2 = xr[2];
            xi[0] = x0.x; xi[1] = x0.y; xi[2]  = x0.z; xi[3]  = x0.w;
            xi[4] = x1.x; xi[5] = x1.y; xi[6]  = x1.z; xi[7]  = x1.w;
            xi[8] = x2.x; xi[9] = x2.y; xi[10] = x2.z; xi[11] = x2.w;

            float o[D];
#pragma unroll
            for (int oo = 0; oo < D; ++oo) {
                float a = sb[oo];
#pragma unroll
                for (int d = 0; d < D; ++d) {
                    a += m[d] * sWl[oo * D + d];
                    a += xi[d] * sWr[oo * D + d];
                }
                o[oo] = a;
            }
            float4* orow = (float4*)(out) + (size_t)node * 3;
            orow[0] = make_float4(o[0], o[1], o[2], o[3]);
            orow[1] = make_float4(o[4], o[5], o[6], o[7]);
            orow[2] = make_float4(o[8], o[9], o[10], o[11]);
        }
    }
}

// ================= R4 mid-tier (proven 272 us pipeline) =====================

__global__ __launch_bounds__(256) void hist_kernel(
    const int* __restrict__ ei, int* __restrict__ bins)
{
    __shared__ int h[NB];
    for (int i = threadIdx.x; i < NB; i += 256) h[i] = 0;
    __syncthreads();
    const int* dei = ei + N_EDGES;
    int start = blockIdx.x * EPB;
    int end = min(start + EPB, N_EDGES);
    int e = start + (int)threadIdx.x;
    while (e + 768 < end) {
        int d0 = dei[e], d1 = dei[e + 256], d2 = dei[e + 512], d3 = dei[e + 768];
        atomicAdd(&h[d0 >> SLOG], 1);
        atomicAdd(&h[d1 >> SLOG], 1);
        atomicAdd(&h[d2 >> SLOG], 1);
        atomicAdd(&h[d3 >> SLOG], 1);
        e += 1024;
    }
    while (e < end) { atomicAdd(&h[dei[e] >> SLOG], 1); e += 256; }
    __syncthreads();
    for (int i = threadIdx.x; i < NB; i += 256) {
        int c = h[i];
        if (c) atomicAdd(&bins[i], c);
    }
}

__global__ __launch_bounds__(1024) void scan_kernel(
    const int* __restrict__ bins, int* __restrict__ base, int* __restrict__ cursor)
{
    __shared__ int buf[1024];
    __shared__ int carry;
    int tid = threadIdx.x;
    if (tid == 0) carry = 0;
    __syncthreads();
    for (int c0 = 0; c0 < NB; c0 += 1024) {
        int i = c0 + tid;
        int v = (i < NB) ? bins[i] : 0;
        buf[tid] = v;
        __syncthreads();
        for (int o = 1; o < 1024; o <<= 1) {
            int t = (tid >= o) ? buf[tid - o] : 0;
            __syncthreads();
            buf[tid] += t;
            __syncthreads();
        }
        int excl = buf[tid] - v + carry;
        if (i < NB) { base[i] = excl; cursor[i] = excl; }
        __syncthreads();
        if (tid == 0) carry += buf[1023];
        __syncthreads();
    }
    if (tid == 0) base[NB] = N_EDGES;
}

__global__ __launch_bounds__(512) void scatter_sort_kernel(
    const int* __restrict__ ei, int* __restrict__ cursor,
    unsigned int* __restrict__ sorted)
{
    __shared__ int h[NB];
    for (int i = threadIdx.x; i < NB; i += STHR) h[i] = 0;
    __syncthreads();
    const int* dei = ei + N_EDGES;
    int start = blockIdx.x * SEPB;
    int end = min(start + SEPB, N_EDGES);
    int e = start + (int)threadIdx.x;
    while (e + 3 * STHR < end) {
        int d0 = dei[e], d1 = dei[e + STHR], d2 = dei[e + 2 * STHR], d3 = dei[e + 3 * STHR];
        atomicAdd(&h[d0 >> SLOG], 1);
        atomicAdd(&h[d1 >> SLOG], 1);
        atomicAdd(&h[d2 >> SLOG], 1);
        atomicAdd(&h[d3 >> SLOG], 1);
        e += 4 * STHR;
    }
    while (e < end) { atomicAdd(&h[dei[e] >> SLOG], 1); e += STHR; }
    __syncthreads();
    for (int i = threadIdx.x; i < NB; i += STHR) {
        int c = h[i];
        h[i] = c ? atomicAdd(&cursor[i], c) : 0;
    }
    __syncthreads();
    e = start + (int)threadIdx.x;
    while (e + 3 * STHR < end) {
        int s0 = ei[e], s1 = ei[e + STHR], s2 = ei[e + 2 * STHR], s3 = ei[e + 3 * STHR];
        int d0 = dei[e], d1 = dei[e + STHR], d2 = dei[e + 2 * STHR], d3 = dei[e + 3 * STHR];
        int p0 = atomicAdd(&h[d0 >> SLOG], 1);
        int p1 = atomicAdd(&h[d1 >> SLOG], 1);
        int p2 = atomicAdd(&h[d2 >> SLOG], 1);
        int p3 = atomicAdd(&h[d3 >> SLOG], 1);
        sorted[p0] = ((unsigned)s0 << SLOG) | (unsigned)(d0 & (SSZ - 1));
        sorted[p1] = ((unsigned)s1 << SLOG) | (unsigned)(d1 & (SSZ - 1));
        sorted[p2] = ((unsigned)s2 << SLOG) | (unsigned)(d2 & (SSZ - 1));
        sorted[p3] = ((unsigned)s3 << SLOG) | (unsigned)(d3 & (SSZ - 1));
        e += 4 * STHR;
    }
    while (e < end) {
        int s = ei[e], d = dei[e];
        int pos = atomicAdd(&h[d >> SLOG], 1);
        sorted[pos] = ((unsigned)s << SLOG) | (unsigned)(d & (SSZ - 1));
        e += STHR;
    }
}

__global__ __launch_bounds__(256) void agg_reg4_kernel(
    const unsigned int* __restrict__ sorted, const int* __restrict__ base,
    const unsigned int* __restrict__ xb,
    const float* __restrict__ x, const float* __restrict__ Wl,
    const float* __restrict__ Wr, const float* __restrict__ bias,
    float* __restrict__ out)
{
    __shared__ float sWl[D * D], sWr[D * D], sb[D];
    __shared__ int cnt[SSZ];
    __shared__ int sbuf[SSZ];
    __shared__ int segbase[SSZ + 1];
    __shared__ int cursor[SSZ];
    __shared__ int cnt_tot[SSZ];
    __shared__ unsigned vals[CAP4 * 6];

    int t = threadIdx.x;
    int b = blockIdx.x;

    if (t < D * D) { sWl[t] = Wl[t]; sWr[t] = Wr[t]; }
    if (t < D) sb[t] = bias[t];
    if (t < SSZ) cnt_tot[t] = 0;

    float acc[D];
#pragma unroll
    for (int d = 0; d < D; ++d) acc[d] = 0.f;

    int loc = t >> 1;
    int sub = t & 1;

    int start = base[b];
    int end = base[b + 1];

    for (int c0 = start; c0 < end; c0 += CAP4) {
        int n = min(CAP4, end - c0);
        if (t < SSZ) cnt[t] = 0;
        __syncthreads();

        unsigned pe[EPT4];
        int ne = 0;
        for (int j = t; j < n; j += 256) pe[ne++] = sorted[c0 + j];
#pragma unroll
        for (int q = 0; q < EPT4; ++q)
            if (q < ne) atomicAdd(&cnt[pe[q] & (SSZ - 1)], 1);
        __syncthreads();

        if (t < SSZ) sbuf[t] = cnt[t];
        __syncthreads();
        for (int o = 1; o < SSZ; o <<= 1) {
            int v = (t < SSZ && t >= o) ? sbuf[t - o] : 0;
            __syncthreads();
            if (t < SSZ) sbuf[t] += v;
            __syncthreads();
        }
        if (t < SSZ) {
            segbase[t + 1] = sbuf[t];
            if (t == 0) segbase[0] = 0;
        }
        __syncthreads();
        if (t < SSZ) { cursor[t] = segbase[t]; cnt_tot[t] += cnt[t]; }
        __syncthreads();

#pragma unroll
        for (int q = 0; q < EPT4; ++q) {
            if (q < ne) {
                unsigned p = pe[q];
                int slot = atomicAdd(&cursor[p & (SSZ - 1)], 1);
                const unsigned* r = xb + (size_t)(p >> SLOG) * 8;
                uint2 q0 = ((const uint2*)r)[0];
                uint2 q1 = ((const uint2*)r)[1];
                uint2 q2 = ((const uint2*)r)[2];
                unsigned* vv = &vals[slot * 6];
                ((uint2*)vv)[0] = q0;
                ((uint2*)vv)[1] = q1;
                ((uint2*)vv)[2] = q2;
            }
        }
        __syncthreads();

        int a0 = segbase[loc], a1 = segbase[loc + 1];
        for (int j = a0 + sub; j < a1; j += 2) {
            const unsigned* vv = &vals[j * 6];
            uint2 q0 = ((const uint2*)vv)[0];
            uint2 q1 = ((const uint2*)vv)[1];
            uint2 q2 = ((const uint2*)vv)[2];
            acc[0]  += bflo(q0.x); acc[1]  += bfhi(q0.x);
            acc[2]  += bflo(q0.y); acc[3]  += bfhi(q0.y);
            acc[4]  += bflo(q1.x); acc[5]  += bfhi(q1.x);
            acc[6]  += bflo(q1.y); acc[7]  += bfhi(q1.y);
            acc[8]  += bflo(q2.x); acc[9]  += bfhi(q2.x);
            acc[10] += bflo(q2.y); acc[11] += bfhi(q2.y);
        }
        __syncthreads();
    }

    float* red = (float*)vals;
#pragma unroll
    for (int d = 0; d < D; ++d) red[sub * 1664 + loc * 13 + d] = acc[d];
    __syncthreads();

    if (t < SSZ) {
        int node = b * SSZ + t;
        if (node < N_NODES) {
            float m[D];
#pragma unroll
            for (int d = 0; d < D; ++d)
                m[d] = red[t * 13 + d] + red[1664 + t * 13 + d];
            float inv = 1.f / fmaxf((float)cnt_tot[t], 1.f);
#pragma unroll
            for (int d = 0; d < D; ++d) m[d] *= inv;

            float xi[D];
            const float4* xr = (const float4*)(x) + (size_t)node * 3;
            float4 x0 = xr[0], x1 = xr[1], x2 = xr[2];
            xi[0] = x0.x; xi[1] = x0.y; xi[2]  = x0.z; xi[3]  = x0.w;
            xi[4] = x1.x; xi[5] = x1.y; xi[6]  = x1.z; xi[7]  = x1.w;
            xi[8] = x2.x; xi[9] = x2.y; xi[10] = x2.z; xi[11] = x2.w;

            float o[D];
#pragma unroll
            for (int oo = 0; oo < D; ++oo) {
                float a = sb[oo];
#pragma unroll
                for (int d = 0; d < D; ++d) {
                    a += m[d] * sWl[oo * D + d];
                    a += xi[d] * sWr[oo * D + d];
                }
                o[oo] = a;
            }
            float4* orow = (float4*)(out) + (size_t)node * 3;
            orow[0] = make_float4(o[0], o[1], o[2], o[3]);
            orow[1] = make_float4(o[4], o[5], o[6], o[7]);
            orow[2] = make_float4(o[8], o[9], o[10], o[11]);
        }
    }
}

// ---------------- Last-resort fallback: global atomics ----------------------

__global__ __launch_bounds__(256) void scatter_kernel(
    const int* __restrict__ ei, const float* __restrict__ x,
    float* __restrict__ agg, float* __restrict__ cnt)
{
    int e = blockIdx.x * blockDim.x + threadIdx.x;
    if (e >= N_EDGES) return;
    int src = ei[e];
    int dst = ei[N_EDGES + e];
    const float4* xr = (const float4*)(x + (size_t)src * D);
    float4 a = xr[0], b4 = xr[1], c = xr[2];
    float* dr = agg + (size_t)dst * D;
    atomicAdd(dr + 0,  a.x);  atomicAdd(dr + 1,  a.y);
    atomicAdd(dr + 2,  a.z);  atomicAdd(dr + 3,  a.w);
    atomicAdd(dr + 4,  b4.x); atomicAdd(dr + 5,  b4.y);
    atomicAdd(dr + 6,  b4.z); atomicAdd(dr + 7,  b4.w);
    atomicAdd(dr + 8,  c.x);  atomicAdd(dr + 9,  c.y);
    atomicAdd(dr + 10, c.z);  atomicAdd(dr + 11, c.w);
    atomicAdd(cnt + dst, 1.0f);
}

__global__ __launch_bounds__(256) void finalize_kernel(
    const float* __restrict__ x, const float* __restrict__ Wl,
    const float* __restrict__ Wr, const float* __restrict__ bias,
    const float* __restrict__ agg, const float* __restrict__ cnt,
    float* __restrict__ out)
{
    __shared__ float sWl[D * D], sWr[D * D], sb[D];
    int t = threadIdx.x;
    if (t < D * D) { sWl[t] = Wl[t]; sWr[t] = Wr[t]; }
    if (t < D) sb[t] = bias[t];
    __syncthreads();
    int i = blockIdx.x * blockDim.x + t;
    if (i >= N_NODES) return;
    float inv = 1.0f / fmaxf(cnt[i], 1.0f);
    float m[D], xi[D];
    const float4* ar = (const float4*)(agg + (size_t)i * D);
    const float4* xr = (const float4*)(x + (size_t)i * D);
    float4 a0 = ar[0], a1 = ar[1], a2 = ar[2];
    float4 x0 = xr[0], x1 = xr[1], x2 = xr[2];
    m[0] = a0.x * inv; m[1] = a0.y * inv; m[2]  = a0.z * inv; m[3]  = a0.w * inv;
    m[4] = a1.x * inv; m[5] = a1.y * inv; m[6]  = a1.z * inv; m[7]  = a1.w * inv;
    m[8] = a2.x * inv; m[9] = a2.y * inv; m[10] = a2.z * inv; m[11] = a2.w * inv;
    xi[0] = x0.x; xi[1] = x0.y; xi[2]  = x0.z; xi[3]  = x0.w;
    xi[4] = x1.x; xi[5] = x1.y; xi[6]  = x1.z; xi[7]  = x1.w;
    xi[8] = x2.x; xi[9] = x2.y; xi[10] = x2.z; xi[11] = x2.w;
    float o[D];
#pragma unroll
    for (int oo = 0; oo < D; ++oo) {
        float acc = sb[oo];
#pragma unroll
        for (int d = 0; d < D; ++d) {
            acc += m[d] * sWl[oo * D + d];
            acc += xi[d] * sWr[oo * D + d];
        }
        o[oo] = acc;
    }
    float4* orow = (float4*)(out + (size_t)i * D);
    orow[0] = make_float4(o[0], o[1], o[2], o[3]);
    orow[1] = make_float4(o[4], o[5], o[6], o[7]);
    orow[2] = make_float4(o[8], o[9], o[10], o[11]);
}

extern "C" void kernel_launch(void* const* d_in, const int* in_sizes, int n_in,
                              void* d_out, int out_size, void* d_ws, size_t ws_size,
                              hipStream_t stream) {
    const float* x    = (const float*)d_in[0];
    const float* Wl   = (const float*)d_in[1];
    const float* Wr   = (const float*)d_in[2];
    const float* bias = (const float*)d_in[3];
    const int*   ei   = (const int*)d_in[4];
    float* out = (float*)d_out;

    size_t stripBytes  = (size_t)NB * SBLK * CAPS * sizeof(unsigned int); // 51.25 MB
    size_t xbBytes     = (size_t)N_NODES * 8 * sizeof(unsigned int);      // 3.2 MB
    size_t cntBytes    = (size_t)SBLK * NB * sizeof(int);                 // 0.8 MB
    size_t ovBytes     = (size_t)OVMAX * sizeof(uint2);                   // 0.5 MB
    size_t neededNew   = stripBytes + xbBytes + cntBytes + ovBytes + 64;

    size_t sortedBytes = (size_t)N_EDGES * sizeof(unsigned int);          // 25.6 MB
    size_t binsBytes   = (size_t)NB * sizeof(int);
    size_t baseBytes   = (size_t)(NB + 1) * sizeof(int);
    size_t neededMid   = sortedBytes + xbBytes + binsBytes + baseBytes + binsBytes;
    size_t neededLast  = ((size_t)N_NODES * D + N_NODES) * sizeof(float);

    if (ws_size >= neededNew) {
        char* p = (char*)d_ws;
        unsigned int* strip = (unsigned int*)p;         p += stripBytes;
        unsigned int* xb    = (unsigned int*)p;         p += xbBytes;
        int* cnt    = (int*)p;                          p += cntBytes;
        uint2* ovbuf = (uint2*)p;                       p += ovBytes;
        int* ovctr  = (int*)p;

        prep_kernel<<<(N_NODES + 255) / 256, 256, 0, stream>>>(x, xb, ovctr);
        scatter1_kernel<<<SBLK, STHR, 0, stream>>>(ei, strip, cnt, ovbuf, ovctr);
        agg_strip_kernel<<<NB, 256, 0, stream>>>(strip, cnt, ovbuf, ovctr, xb, x, Wl, Wr, bias, out);
    } else if (ws_size >= neededMid) {
        char* p = (char*)d_ws;
        unsigned int* sorted = (unsigned int*)p;        p += sortedBytes;
        unsigned int* xb     = (unsigned int*)p;        p += xbBytes;
        int* bins   = (int*)p;                          p += binsBytes;
        int* base   = (int*)p;                          p += baseBytes;
        int* cursor = (int*)p;

        hipMemsetAsync(bins, 0, binsBytes, stream);
        prep_kernel<<<(N_NODES + 255) / 256, 256, 0, stream>>>(x, xb, nullptr);
        hist_kernel<<<NBLK, 256, 0, stream>>>(ei, bins);
        scan_kernel<<<1, 1024, 0, stream>>>(bins, base, cursor);
        scatter_sort_kernel<<<SBLK, STHR, 0, stream>>>(ei, cursor, sorted);
        agg_reg4_kernel<<<NB, 256, 0, stream>>>(sorted, base, xb, x, Wl, Wr, bias, out);
    } else {
        float* agg = (float*)d_ws;
        float* cnt = agg + (size_t)N_NODES * D;
        hipMemsetAsync(d_ws, 0, neededLast, stream);
        scatter_kernel<<<(N_EDGES + 255) / 256, 256, 0, stream>>>(ei, x, agg, cnt);
        finalize_kernel<<<(N_NODES + 255) / 256, 256, 0, stream>>>(x, Wl, Wr, bias, agg, cnt, out);
    }
}